// Round 5
// baseline (388.133 us; speedup 1.0000x reference)
//
#include <hip/hip_runtime.h>
#include <hip/hip_bf16.h>

#define N_NODES 50000
#define N_EDGES 1600000
#define IN_FEATS 512
#define N_HIDDEN 128
#define N_CLASSES 40
#define NBKT 782      // ceil(50000/64) buckets of 64 nodes
#define NBLK 800      // partition blocks
#define EPB 2000      // edges per partition block (800*2000 = 1.6M exact)
#define NROWPAD 50048 // 391*128, padded row count for gemm2 A-reads

typedef __attribute__((ext_vector_type(8))) short bf16x8;
typedef __attribute__((ext_vector_type(4))) float f32x4;

__device__ __forceinline__ unsigned short f2bf(float f) {
    unsigned u = __float_as_uint(f);
    u = (u + 0x7FFFu + ((u >> 16) & 1u)) >> 16;   // round-to-nearest-even
    return (unsigned short)u;
}
__device__ __forceinline__ float bf2f(unsigned short h) {
    return __uint_as_float(((unsigned)h) << 16);
}
// packed f32x2 -> bf16x2 (RTNE), lowers to v_cvt_pk_bf16_f32 on gfx950
__device__ __forceinline__ unsigned pk_bf(float a, float b) {
    __hip_bfloat162 h = __float22bfloat162_rn(make_float2(a, b));
    union { __hip_bfloat162 v; unsigned u; } c;
    c.v = h;
    return c.u;   // low 16 = bf(a), high 16 = bf(b)
}

// 8 floats (two float4) -> hi/lo bf16x8 fragments, in registers.
__device__ __forceinline__ void cvt8(float4 a, float4 b, bf16x8& h, bf16x8& l) {
    unsigned h0 = pk_bf(a.x, a.y), h1 = pk_bf(a.z, a.w);
    unsigned h2 = pk_bf(b.x, b.y), h3 = pk_bf(b.z, b.w);
    unsigned l0 = pk_bf(a.x - __uint_as_float(h0 << 16),
                        a.y - __uint_as_float(h0 & 0xffff0000u));
    unsigned l1 = pk_bf(a.z - __uint_as_float(h1 << 16),
                        a.w - __uint_as_float(h1 & 0xffff0000u));
    unsigned l2 = pk_bf(b.x - __uint_as_float(h2 << 16),
                        b.y - __uint_as_float(h2 & 0xffff0000u));
    unsigned l3 = pk_bf(b.z - __uint_as_float(h3 << 16),
                        b.w - __uint_as_float(h3 & 0xffff0000u));
    union U { unsigned u[4]; bf16x8 v; };
    U H; H.u[0] = h0; H.u[1] = h1; H.u[2] = h2; H.u[3] = h3; h = H.v;
    U L; L.u[0] = l0; L.u[1] = l1; L.u[2] = l2; L.u[3] = l3; l = L.v;
}

__device__ __forceinline__ int imin(int a, int b) { return a < b ? a : b; }

// ---------------------------------------------------------------------------
// setup: W1 -> k-chunked bf16 hi/lo [kc][col][ki]; W2 -> transposed [48][128]
__global__ __launch_bounds__(256) void setup_cvt(
    const float* __restrict__ W1, const float* __restrict__ W2,
    unsigned short* __restrict__ W1ch, unsigned short* __restrict__ W1cl,
    unsigned short* __restrict__ W2th, unsigned short* __restrict__ W2tl) {
    int i = blockIdx.x * 256 + threadIdx.x;
    if (i < IN_FEATS * N_HIDDEN) {
        int k = i >> 7, c = i & 127;
        float v = W1[i];
        unsigned short h = f2bf(v);
        int o = (k >> 5) * 4096 + c * 32 + (k & 31);
        W1ch[o] = h;
        W1cl[o] = f2bf(v - bf2f(h));
    } else {
        int j = i - IN_FEATS * N_HIDDEN;    // 0..6143 (grid sized exactly)
        int n = j >> 7, k = j & 127;
        float v = (n < N_CLASSES) ? W2[k * N_CLASSES + n] : 0.f;
        unsigned short h = f2bf(v);
        W2th[n * 128 + k] = h;
        W2tl[n * 128 + k] = f2bf(v - bf2f(h));
    }
}

// ---------------------------------------------------------------------------
// megaA: blocks [0,NBKT) = gemm1 tiles; blocks [NBKT,NBKT+NBLK) = p1_hist.
//
// gemm1 v5: WAVE-PRIVATE 16-ROW TILES — LDS-free, barrier-free, dup-free.
// Key insight (r0-r4 invariance): every staged variant had __syncthreads in
// the K-loop, which forces s_waitcnt vmcnt(0) before s_barrier, draining all
// prefetches every chunk -> ~1 TB/s effective X stream. With one 16-row tile
// per wave, the MFMA A-fragment (lane l holds A[l&15][(l>>4)*8..+8]) is
// EXACTLY a per-lane 32B X load: no LDS, no barrier, and the block's 4 waves
// cover disjoint row groups (no duplication, unlike r2). B (16KB/chunk) is
// read by all 4 waves but stays L1/L2-hot. Deep X prefetch now survives
// across chunks (nothing ever drains vmcnt to 0).

#define MFJ(AH, AL, BH, BL, ACC)                                              \
    ACC = __builtin_amdgcn_mfma_f32_16x16x32_bf16(AH, BH, ACC, 0, 0, 0);      \
    ACC = __builtin_amdgcn_mfma_f32_16x16x32_bf16(AH, BL, ACC, 0, 0, 0);      \
    ACC = __builtin_amdgcn_mfma_f32_16x16x32_bf16(AL, BH, ACC, 0, 0, 0);

__global__ __launch_bounds__(256, 4) void megaA(
    const int* __restrict__ src, const int* __restrict__ dst,
    int* __restrict__ histD, int* __restrict__ histS,
    const float* __restrict__ X, const unsigned short* __restrict__ Wch,
    const unsigned short* __restrict__ Wcl, unsigned short* __restrict__ Hb) {
    __shared__ int hd[NBKT], hs[NBKT];   // hist-only; gemm never touches LDS
    const int tid = threadIdx.x;

    if (blockIdx.x >= NBKT) {
        // ---- p1_hist ----
        int b = blockIdx.x - NBKT;
        for (int i = tid; i < NBKT; i += 256) { hd[i] = 0; hs[i] = 0; }
        __syncthreads();
        int e0 = b * EPB;
        for (int i = tid; i < EPB; i += 256) {
            atomicAdd(&hd[dst[e0 + i] >> 6], 1);
            atomicAdd(&hs[src[e0 + i] >> 6], 1);
        }
        __syncthreads();
        for (int i = tid; i < NBKT; i += 256) {
            histD[b * NBKT + i] = hd[i];
            histS[b * NBKT + i] = hs[i];
        }
        return;
    }
    // ---- gemm1: 64 rows/block, 16 rows/wave x 128 cols, split-precision ----
    const int lane = tid & 63;
    const int wv = tid >> 6;
    const int m = lane & 15;
    const int q = lane >> 4;
    const int q8 = q * 8;
    const int row0 = blockIdx.x * 64;

    const int myrow = imin(row0 + wv * 16 + m, N_NODES - 1);
    const float* xp = &X[(size_t)myrow * IN_FEATS + q8];
    const unsigned short* wb = Wch + m * 32 + q8;
    const unsigned short* wl = Wcl + m * 32 + q8;

    f32x4 acc[8];
#pragma unroll
    for (int n = 0; n < 8; n++) acc[n] = (f32x4){0.f, 0.f, 0.f, 0.f};

    // register pipeline: cx = chunk kc, px = chunk kc+1
    float4 cx0 = *(const float4*)(xp),      cx1 = *(const float4*)(xp + 4);
    float4 px0 = *(const float4*)(xp + 32), px1 = *(const float4*)(xp + 36);

    for (int kc = 0; kc < 16; kc++) {
        float4 nx0 = px0, nx1 = px1;
        if (kc < 14) {
            nx0 = *(const float4*)(xp + (kc + 2) * 32);
            nx1 = *(const float4*)(xp + (kc + 2) * 32 + 4);
        }
        bf16x8 ah, al;
        cvt8(cx0, cx1, ah, al);
        const unsigned short* wbk = wb + kc * 4096;
        const unsigned short* wlk = wl + kc * 4096;
        // col-tiles 0..3
        {
            bf16x8 bh0 = *(const bf16x8*)(wbk);
            bf16x8 bh1 = *(const bf16x8*)(wbk + 512);
            bf16x8 bh2 = *(const bf16x8*)(wbk + 1024);
            bf16x8 bh3 = *(const bf16x8*)(wbk + 1536);
            bf16x8 bl0 = *(const bf16x8*)(wlk);
            bf16x8 bl1 = *(const bf16x8*)(wlk + 512);
            bf16x8 bl2 = *(const bf16x8*)(wlk + 1024);
            bf16x8 bl3 = *(const bf16x8*)(wlk + 1536);
            MFJ(ah, al, bh0, bl0, acc[0])
            MFJ(ah, al, bh1, bl1, acc[1])
            MFJ(ah, al, bh2, bl2, acc[2])
            MFJ(ah, al, bh3, bl3, acc[3])
        }
        // col-tiles 4..7
        {
            bf16x8 bh4 = *(const bf16x8*)(wbk + 2048);
            bf16x8 bh5 = *(const bf16x8*)(wbk + 2560);
            bf16x8 bh6 = *(const bf16x8*)(wbk + 3072);
            bf16x8 bh7 = *(const bf16x8*)(wbk + 3584);
            bf16x8 bl4 = *(const bf16x8*)(wlk + 2048);
            bf16x8 bl5 = *(const bf16x8*)(wlk + 2560);
            bf16x8 bl6 = *(const bf16x8*)(wlk + 3072);
            bf16x8 bl7 = *(const bf16x8*)(wlk + 3584);
            MFJ(ah, al, bh4, bl4, acc[4])
            MFJ(ah, al, bh5, bl5, acc[5])
            MFJ(ah, al, bh6, bl6, acc[6])
            MFJ(ah, al, bh7, bl7, acc[7])
        }
        cx0 = px0; cx1 = px1;
        px0 = nx0; px1 = nx1;
    }

    // C/D layout: col = lane&15 (=m), row = q*4 + reg
    const int orow = row0 + wv * 16 + q * 4;
#pragma unroll
    for (int r = 0; r < 4; r++) {
        int grow = orow + r;
        if (grow < N_NODES) {
#pragma unroll
            for (int n = 0; n < 8; n++)
                Hb[(size_t)grow * N_HIDDEN + n * 16 + m] = f2bf(acc[n][r]);
        }
    }
}

// ---------------------------------------------------------------------------
// P2a: one wave per bucket — parallel scan over the 800-block dimension.
__global__ __launch_bounds__(256) void p2_local(
    const int* __restrict__ histD, const int* __restrict__ histS,
    int* __restrict__ baseD, int* __restrict__ baseS,
    int* __restrict__ totD, int* __restrict__ totS) {
    int wv = threadIdx.x >> 6, lane = threadIdx.x & 63;
    int w = blockIdx.x * 4 + wv;
    if (w >= NBKT) return;
    int runD = 0, runS = 0;
#pragma unroll
    for (int c = 0; c < 13; c++) {
        int blk = c * 64 + lane;
        int vD = 0, vS = 0;
        if (blk < NBLK) {
            vD = histD[blk * NBKT + w];
            vS = histS[blk * NBKT + w];
        }
        int iD = vD, iS = vS;
#pragma unroll
        for (int off = 1; off < 64; off <<= 1) {
            int tD = __shfl_up(iD, off);
            int tS = __shfl_up(iS, off);
            if (lane >= off) { iD += tD; iS += tS; }
        }
        if (blk < NBLK) {
            baseD[blk * NBKT + w] = runD + iD - vD;
            baseS[blk * NBKT + w] = runS + iS - vS;
        }
        runD += __shfl(iD, 63);
        runS += __shfl(iS, 63);
    }
    if (lane == 0) { totD[w] = runD; totS[w] = runS; }
}

// P2b: single-block scan over the 782 bucket totals only.
__global__ __launch_bounds__(1024) void p2_small(
    const int* __restrict__ totD, const int* __restrict__ totS,
    int* __restrict__ bucket_base, int* __restrict__ srcb_base,
    int* __restrict__ offsets) {
    __shared__ int part[1024];
    int t = threadIdx.x;
    int v = (t < NBKT) ? totD[t] : 0;
    part[t] = v;
    __syncthreads();
    for (int off = 1; off < 1024; off <<= 1) {
        int x = (t >= off) ? part[t - off] : 0;
        __syncthreads();
        part[t] += x;
        __syncthreads();
    }
    if (t < NBKT) bucket_base[t] = part[t] - v;
    if (t == 0) { bucket_base[NBKT] = N_EDGES; offsets[N_NODES] = N_EDGES; }
    __syncthreads();
    v = (t < NBKT) ? totS[t] : 0;
    part[t] = v;
    __syncthreads();
    for (int off = 1; off < 1024; off <<= 1) {
        int x = (t >= off) ? part[t - off] : 0;
        __syncthreads();
        part[t] += x;
        __syncthreads();
    }
    if (t < NBKT) srcb_base[t] = part[t] - v;
    if (t == 0) srcb_base[NBKT] = N_EDGES;
}

// ---------------------------------------------------------------------------
// P3: scatter edges into bucket-partitioned arrays via LDS cursors.
__global__ __launch_bounds__(256) void p3_scatter(
    const int* __restrict__ src, const int* __restrict__ dst,
    const int* __restrict__ baseD, const int* __restrict__ baseS,
    const int* __restrict__ bucket_base, const int* __restrict__ srcb_base,
    unsigned int* __restrict__ edata, unsigned char* __restrict__ srcv) {
    __shared__ int curD[NBKT], curS[NBKT];
    int t = threadIdx.x, b = blockIdx.x;
    for (int i = t; i < NBKT; i += 256) {
        curD[i] = bucket_base[i] + baseD[b * NBKT + i];
        curS[i] = srcb_base[i] + baseS[b * NBKT + i];
    }
    __syncthreads();
    int e0 = b * EPB;
    for (int i = t; i < EPB; i += 256) {
        int s = src[e0 + i], d = dst[e0 + i];
        int slotD = atomicAdd(&curD[d >> 6], 1);
        edata[slotD] = (unsigned)s | ((unsigned)(d & 63) << 16);
        int slotS = atomicAdd(&curS[s >> 6], 1);
        srcv[slotS] = (unsigned char)(s & 63);
    }
}

// ---------------------------------------------------------------------------
// P4 fused: src-side count -> norm_src; dst-side count+scatter -> offsets,
// norm_dst, sorted_src. One block per bucket.
__global__ __launch_bounds__(256) void p4_fused(
    const int* __restrict__ srcb_base, const unsigned char* __restrict__ srcv,
    const int* __restrict__ bucket_base, const unsigned int* __restrict__ edata,
    int* __restrict__ offsets, float* __restrict__ norm_src,
    float* __restrict__ norm_dst, int* __restrict__ sorted_src) {
    __shared__ int cntS[64], cntD[64], cur[64];
    int t = threadIdx.x, b = blockIdx.x;
    if (t < 64) { cntS[t] = 0; cntD[t] = 0; }
    __syncthreads();
    int s0 = srcb_base[b], s1 = srcb_base[b + 1];
    for (int i = s0 + t; i < s1; i += 256) atomicAdd(&cntS[srcv[i]], 1);
    int d0 = bucket_base[b], d1 = bucket_base[b + 1];
    for (int i = d0 + t; i < d1; i += 256)
        atomicAdd(&cntD[(edata[i] >> 16) & 63], 1);
    __syncthreads();
    if (t == 0) {
        int run = 0;
        for (int i = 0; i < 64; i++) { cur[i] = run; run += cntD[i]; }
    }
    __syncthreads();
    if (t < 64) {
        int node = b * 64 + t;
        if (node < N_NODES) {
            norm_src[node] = rsqrtf(fmaxf((float)cntS[t], 1.0f));
            offsets[node] = d0 + cur[t];
            norm_dst[node] = rsqrtf(fmaxf((float)cntD[t], 1.0f));
        }
    }
    __syncthreads();
    for (int i = d0 + t; i < d1; i += 256) {
        unsigned e = edata[i];
        int slot = atomicAdd(&cur[(e >> 16) & 63], 1);
        sorted_src[d0 + slot] = (int)(e & 0xFFFFu);
    }
}

// ---------------------------------------------------------------------------
// agg1: one wave per dst node; per-edge norm_src fma (Hb is unscaled),
// 16 edges in flight (4 b128/lane), xor-16/32 butterfly, fused
// norm_dst+bias+relu, H1 out bf16 hi/lo with norm_src[wid] folded (for gemm2).
#define FMA8(W, NS)                                                   \
    acc0 = fmaf(__uint_as_float((W).x << 16), NS, acc0);              \
    acc1 = fmaf(__uint_as_float((W).x & 0xffff0000u), NS, acc1);      \
    acc2 = fmaf(__uint_as_float((W).y << 16), NS, acc2);              \
    acc3 = fmaf(__uint_as_float((W).y & 0xffff0000u), NS, acc3);      \
    acc4 = fmaf(__uint_as_float((W).z << 16), NS, acc4);              \
    acc5 = fmaf(__uint_as_float((W).z & 0xffff0000u), NS, acc5);      \
    acc6 = fmaf(__uint_as_float((W).w << 16), NS, acc6);              \
    acc7 = fmaf(__uint_as_float((W).w & 0xffff0000u), NS, acc7);

__global__ __launch_bounds__(256) void agg1_kernel(
    const int* __restrict__ offsets, const int* __restrict__ sorted_src,
    const unsigned short* __restrict__ Hb, const float* __restrict__ norm_dst,
    const float* __restrict__ norm_src, const float* __restrict__ b1,
    unsigned short* __restrict__ H1h, unsigned short* __restrict__ H1l) {
    int wid = (blockIdx.x * 256 + threadIdx.x) >> 6;
    int lane = threadIdx.x & 63;
    if (wid >= N_NODES) return;
    int start = offsets[wid], end = offsets[wid + 1];
    int quad = lane >> 4;
    int c8 = (lane & 15) * 8;
    float acc0 = 0.f, acc1 = 0.f, acc2 = 0.f, acc3 = 0.f;
    float acc4 = 0.f, acc5 = 0.f, acc6 = 0.f, acc7 = 0.f;
    int base = start;
    for (; base + 16 <= end; base += 16) {
        int e0 = sorted_src[base + quad];
        int e1 = sorted_src[base + 4 + quad];
        int e2 = sorted_src[base + 8 + quad];
        int e3 = sorted_src[base + 12 + quad];
        float n0 = norm_src[e0], n1 = norm_src[e1];
        float n2 = norm_src[e2], n3 = norm_src[e3];
        uint4 w0 = *(const uint4*)&Hb[(size_t)e0 * N_HIDDEN + c8];
        uint4 w1 = *(const uint4*)&Hb[(size_t)e1 * N_HIDDEN + c8];
        uint4 w2 = *(const uint4*)&Hb[(size_t)e2 * N_HIDDEN + c8];
        uint4 w3 = *(const uint4*)&Hb[(size_t)e3 * N_HIDDEN + c8];
        FMA8(w0, n0);
        FMA8(w1, n1);
        FMA8(w2, n2);
        FMA8(w3, n3);
    }
    for (; base + 4 <= end; base += 4) {
        int e = sorted_src[base + quad];
        float n = norm_src[e];
        uint4 w = *(const uint4*)&Hb[(size_t)e * N_HIDDEN + c8];
        FMA8(w, n);
    }
    int rem = end - base;
    if (quad < rem) {
        int e = sorted_src[base + quad];
        float n = norm_src[e];
        uint4 w = *(const uint4*)&Hb[(size_t)e * N_HIDDEN + c8];
        FMA8(w, n);
    }
    acc0 += __shfl_xor(acc0, 16); acc0 += __shfl_xor(acc0, 32);
    acc1 += __shfl_xor(acc1, 16); acc1 += __shfl_xor(acc1, 32);
    acc2 += __shfl_xor(acc2, 16); acc2 += __shfl_xor(acc2, 32);
    acc3 += __shfl_xor(acc3, 16); acc3 += __shfl_xor(acc3, 32);
    acc4 += __shfl_xor(acc4, 16); acc4 += __shfl_xor(acc4, 32);
    acc5 += __shfl_xor(acc5, 16); acc5 += __shfl_xor(acc5, 32);
    acc6 += __shfl_xor(acc6, 16); acc6 += __shfl_xor(acc6, 32);
    acc7 += __shfl_xor(acc7, 16); acc7 += __shfl_xor(acc7, 32);
    if (quad == 0) {
        float nd = norm_dst[wid];
        float ns = norm_src[wid];
        float4 ba = *(const float4*)&b1[c8];
        float4 bb = *(const float4*)&b1[c8 + 4];
        float o[8];
        o[0] = fmaxf(acc0 * nd + ba.x, 0.f) * ns;
        o[1] = fmaxf(acc1 * nd + ba.y, 0.f) * ns;
        o[2] = fmaxf(acc2 * nd + ba.z, 0.f) * ns;
        o[3] = fmaxf(acc3 * nd + ba.w, 0.f) * ns;
        o[4] = fmaxf(acc4 * nd + bb.x, 0.f) * ns;
        o[5] = fmaxf(acc5 * nd + bb.y, 0.f) * ns;
        o[6] = fmaxf(acc6 * nd + bb.z, 0.f) * ns;
        o[7] = fmaxf(acc7 * nd + bb.w, 0.f) * ns;
        unsigned short hh[8], ll[8];
#pragma unroll
        for (int t = 0; t < 8; t++) {
            hh[t] = f2bf(o[t]);
            ll[t] = f2bf(o[t] - bf2f(hh[t]));
        }
        uint4 ph = make_uint4((unsigned)hh[0] | ((unsigned)hh[1] << 16),
                              (unsigned)hh[2] | ((unsigned)hh[3] << 16),
                              (unsigned)hh[4] | ((unsigned)hh[5] << 16),
                              (unsigned)hh[6] | ((unsigned)hh[7] << 16));
        uint4 pl = make_uint4((unsigned)ll[0] | ((unsigned)ll[1] << 16),
                              (unsigned)ll[2] | ((unsigned)ll[3] << 16),
                              (unsigned)ll[4] | ((unsigned)ll[5] << 16),
                              (unsigned)ll[6] | ((unsigned)ll[7] << 16));
        *(uint4*)&H1h[(size_t)wid * N_HIDDEN + c8] = ph;
        *(uint4*)&H1l[(size_t)wid * N_HIDDEN + c8] = pl;
    }
}

// ---------------------------------------------------------------------------
// GEMM2 via bf16 MFMA: H2u[n][0:40] = H1n @ W2, PACKED hi|lo bf16 in u32
// (full f32 precision to 2^-17 rel), 48-dword rows for 16B-aligned gathers.
__global__ __launch_bounds__(256) void gemm2_kernel(
    const unsigned short* __restrict__ H1h, const unsigned short* __restrict__ H1l,
    const unsigned short* __restrict__ W2th, const unsigned short* __restrict__ W2tl,
    unsigned int* __restrict__ H2u) {
    __shared__ __align__(16) unsigned short Bh[48][136];
    __shared__ __align__(16) unsigned short Bl[48][136];
    const int tid = threadIdx.x;
    for (int i = tid; i < 48 * 16; i += 256) {
        int n = i >> 4, kq = (i & 15) * 8;
        *(uint4*)&Bh[n][kq] = *(const uint4*)&W2th[n * 128 + kq];
        *(uint4*)&Bl[n][kq] = *(const uint4*)&W2tl[n * 128 + kq];
    }
    __syncthreads();
    const int lane = tid & 63;
    const int wave = tid >> 6;
    const int m = lane & 15;
    const int q = lane >> 4;
    const int row0 = blockIdx.x * 128 + wave * 32;

    f32x4 acc[2][3];
#pragma unroll
    for (int i = 0; i < 2; i++)
#pragma unroll
        for (int j = 0; j < 3; j++) acc[i][j] = (f32x4){0.f, 0.f, 0.f, 0.f};

#pragma unroll
    for (int kc = 0; kc < 4; kc++) {
        bf16x8 bh[3], bl[3];
#pragma unroll
        for (int j = 0; j < 3; j++) {
            bh[j] = *(const bf16x8*)&Bh[j * 16 + m][kc * 32 + q * 8];
            bl[j] = *(const bf16x8*)&Bl[j * 16 + m][kc * 32 + q * 8];
        }
#pragma unroll
        for (int i = 0; i < 2; i++) {
            size_t ro = (size_t)(row0 + i * 16 + m) * N_HIDDEN + kc * 32 + q * 8;
            bf16x8 ah = *(const bf16x8*)&H1h[ro];
            bf16x8 al = *(const bf16x8*)&H1l[ro];
#pragma unroll
            for (int j = 0; j < 3; j++) {
                acc[i][j] = __builtin_amdgcn_mfma_f32_16x16x32_bf16(ah, bh[j], acc[i][j], 0, 0, 0);
                acc[i][j] = __builtin_amdgcn_mfma_f32_16x16x32_bf16(ah, bl[j], acc[i][j], 0, 0, 0);
                acc[i][j] = __builtin_amdgcn_mfma_f32_16x16x32_bf16(al, bh[j], acc[i][j], 0, 0, 0);
            }
        }
    }
#pragma unroll
    for (int i = 0; i < 2; i++) {
#pragma unroll
        for (int r = 0; r < 4; r++) {
            int row = row0 + i * 16 + q * 4 + r;
            if (row < N_NODES) {
#pragma unroll
                for (int j = 0; j < 3; j++) {
                    int col = j * 16 + m;
                    if (col < N_CLASSES) {
                        float v = acc[i][j][r];
                        unsigned short h = f2bf(v);
                        unsigned short l = f2bf(v - bf2f(h));
                        H2u[(size_t)row * 48 + col] = ((unsigned)h << 16) | (unsigned)l;
                    }
                }
            }
        }
    }
}

// ---------------------------------------------------------------------------
// agg2: one wave per dst node; 16 edges in flight (4 uint4/lane), packed
// hi|lo bf16 reconstruction, butterfly reduce.
#define ACC4(V)                                                               \
    acc.x += __uint_as_float((V).x & 0xffff0000u) + __uint_as_float((V).x << 16); \
    acc.y += __uint_as_float((V).y & 0xffff0000u) + __uint_as_float((V).y << 16); \
    acc.z += __uint_as_float((V).z & 0xffff0000u) + __uint_as_float((V).z << 16); \
    acc.w += __uint_as_float((V).w & 0xffff0000u) + __uint_as_float((V).w << 16);

__global__ __launch_bounds__(256) void agg2_kernel(
    const int* __restrict__ offsets, const int* __restrict__ sorted_src,
    const unsigned int* __restrict__ H2u, const float* __restrict__ norm_dst,
    const float* __restrict__ b2, float* __restrict__ OUT) {
    int wid = (blockIdx.x * 256 + threadIdx.x) >> 6;
    int lane = threadIdx.x & 63;
    if (wid >= N_NODES) return;
    int start = offsets[wid], end = offsets[wid + 1];
    int quad = lane >> 4;
    int c4 = (lane & 15) * 4;
    bool active = c4 < N_CLASSES;
    float4 acc = make_float4(0.f, 0.f, 0.f, 0.f);
    int base = start;
    for (; base + 16 <= end; base += 16) {
        int e0 = sorted_src[base + quad];
        int e1 = sorted_src[base + 4 + quad];
        int e2 = sorted_src[base + 8 + quad];
        int e3 = sorted_src[base + 12 + quad];
        if (active) {
            uint4 v0 = *(const uint4*)&H2u[(size_t)e0 * 48 + c4];
            uint4 v1 = *(const uint4*)&H2u[(size_t)e1 * 48 + c4];
            uint4 v2 = *(const uint4*)&H2u[(size_t)e2 * 48 + c4];
            uint4 v3 = *(const uint4*)&H2u[(size_t)e3 * 48 + c4];
            ACC4(v0); ACC4(v1); ACC4(v2); ACC4(v3);
        }
    }
    for (; base + 4 <= end; base += 4) {
        int e = sorted_src[base + quad];
        if (active) {
            uint4 v = *(const uint4*)&H2u[(size_t)e * 48 + c4];
            ACC4(v);
        }
    }
    int rem = end - base;
    if (quad < rem && active) {
        int e = sorted_src[base + quad];
        uint4 v = *(const uint4*)&H2u[(size_t)e * 48 + c4];
        ACC4(v);
    }
    acc.x += __shfl_xor(acc.x, 16); acc.x += __shfl_xor(acc.x, 32);
    acc.y += __shfl_xor(acc.y, 16); acc.y += __shfl_xor(acc.y, 32);
    acc.z += __shfl_xor(acc.z, 16); acc.z += __shfl_xor(acc.z, 32);
    acc.w += __shfl_xor(acc.w, 16); acc.w += __shfl_xor(acc.w, 32);
    if (lane < 10) {
        float nd = norm_dst[wid];
        float4 b = *(const float4*)&b2[lane * 4];
        acc.x = acc.x * nd + b.x;
        acc.y = acc.y * nd + b.y;
        acc.z = acc.z * nd + b.z;
        acc.w = acc.w * nd + b.w;
        *(float4*)&OUT[(size_t)wid * N_CLASSES + lane * 4] = acc;
    }
}

// ---------------------------------------------------------------------------
extern "C" void kernel_launch(void* const* d_in, const int* in_sizes, int n_in,
                              void* d_out, int out_size, void* d_ws, size_t ws_size,
                              hipStream_t stream) {
    const float* X   = (const float*)d_in[0];
    const float* W1  = (const float*)d_in[1];
    const float* b1  = (const float*)d_in[2];
    const float* W2  = (const float*)d_in[3];
    const float* b2  = (const float*)d_in[4];
    const int*   src = (const int*)d_in[5];
    const int*   dst = (const int*)d_in[6];
    float* out = (float*)d_out;

    // workspace layout (4B units). regionA time-shared:
    //   phase 1: histD|histS|baseD|baseS|totD|totS      [dead after p3]
    //   phase 3: H2u packed u32 50000x48 (2.4M dwords)  [written at gemm2]
    // Hb has its own region (written by megaA while phase-1 data live).
    float* norm_src   = (float*)d_ws;                     // 50000
    float* norm_dst   = norm_src + N_NODES;               // 50000
    int*   offsets    = (int*)(norm_dst + N_NODES);       // 50016 (incl pad)
    int*   bucket_base = offsets + N_NODES + 16;          // 800
    int*   srcb_base  = bucket_base + 800;                // 800
    unsigned int* edata = (unsigned int*)(srcb_base + 800);       // 1.6M
    unsigned char* srcv = (unsigned char*)(edata + N_EDGES);      // 400K dwords
    int*   sorted_src = (int*)(edata + N_EDGES) + 400000; // 1.6M
    int*   regionA    = sorted_src + N_EDGES;             // 3.2M dwords
    int*   histD      = regionA;
    int*   histS      = regionA + 625600;
    int*   baseD      = regionA + 1251200;
    int*   baseS      = regionA + 1876800;
    int*   totD       = regionA + 2502400;                // 800
    int*   totS       = regionA + 2503200;                // 800
    unsigned int* H2u = (unsigned int*)regionA;           // phase 3 (2.4M)
    unsigned short* H1h = (unsigned short*)(regionA + 3200000);   // 50048x128 bf16
    unsigned short* H1l = H1h + (size_t)NROWPAD * N_HIDDEN;
    unsigned short* W1ch = H1l + (size_t)NROWPAD * N_HIDDEN;      // k-chunked 512*128
    unsigned short* W1cl = W1ch + IN_FEATS * N_HIDDEN;
    unsigned short* W2th = W1cl + IN_FEATS * N_HIDDEN;            // 48*128
    unsigned short* W2tl = W2th + 48 * 128;
    unsigned short* Hb   = W2tl + 48 * 128;               // 50000x128 bf16 (own region)

    setup_cvt<<<(IN_FEATS * N_HIDDEN + 48 * 128) / 256, 256, 0, stream>>>(
        W1, W2, W1ch, W1cl, W2th, W2tl);
    megaA<<<NBLK + NBKT, 256, 0, stream>>>(src, dst, histD, histS, X, W1ch, W1cl, Hb);
    p2_local<<<(NBKT + 3) / 4, 256, 0, stream>>>(histD, histS, baseD, baseS, totD, totS);
    p2_small<<<1, 1024, 0, stream>>>(totD, totS, bucket_base, srcb_base, offsets);
    p3_scatter<<<NBLK, 256, 0, stream>>>(src, dst, baseD, baseS, bucket_base, srcb_base,
                                         edata, srcv);
    p4_fused<<<NBKT, 256, 0, stream>>>(srcb_base, srcv, bucket_base, edata,
                                       offsets, norm_src, norm_dst, sorted_src);
    agg1_kernel<<<(N_NODES + 3) / 4, 256, 0, stream>>>(offsets, sorted_src, Hb, norm_dst,
                                                       norm_src, b1, H1h, H1l);
    gemm2_kernel<<<(N_NODES + 127) / 128, 256, 0, stream>>>(H1h, H1l, W2th, W2tl, H2u);
    agg2_kernel<<<(N_NODES + 3) / 4, 256, 0, stream>>>(offsets, sorted_src, H2u, norm_dst, b2, out);
}

// Round 6
// 378.153 us; speedup vs baseline: 1.0264x; 1.0264x over previous
//
#include <hip/hip_runtime.h>
#include <hip/hip_bf16.h>

#define N_NODES 50000
#define N_EDGES 1600000
#define IN_FEATS 512
#define N_HIDDEN 128
#define N_CLASSES 40
#define NBKT 782      // ceil(50000/64) buckets of 64 nodes
#define NBLK 800      // partition blocks
#define EPB 2000      // edges per partition block (800*2000 = 1.6M exact)
#define NROWPAD 50048 // 391*128, padded row count for gemm2 A-reads

typedef __attribute__((ext_vector_type(8))) short bf16x8;
typedef __attribute__((ext_vector_type(4))) float f32x4;

__device__ __forceinline__ unsigned short f2bf(float f) {
    unsigned u = __float_as_uint(f);
    u = (u + 0x7FFFu + ((u >> 16) & 1u)) >> 16;   // round-to-nearest-even
    return (unsigned short)u;
}
__device__ __forceinline__ float bf2f(unsigned short h) {
    return __uint_as_float(((unsigned)h) << 16);
}
// packed f32x2 -> bf16x2 (RTNE), lowers to v_cvt_pk_bf16_f32 on gfx950
__device__ __forceinline__ unsigned pk_bf(float a, float b) {
    __hip_bfloat162 h = __float22bfloat162_rn(make_float2(a, b));
    union { __hip_bfloat162 v; unsigned u; } c;
    c.v = h;
    return c.u;   // low 16 = bf(a), high 16 = bf(b)
}

// 8 floats (two float4) -> hi/lo bf16x8 fragments, in registers.
__device__ __forceinline__ void cvt8(float4 a, float4 b, bf16x8& h, bf16x8& l) {
    unsigned h0 = pk_bf(a.x, a.y), h1 = pk_bf(a.z, a.w);
    unsigned h2 = pk_bf(b.x, b.y), h3 = pk_bf(b.z, b.w);
    unsigned l0 = pk_bf(a.x - __uint_as_float(h0 << 16),
                        a.y - __uint_as_float(h0 & 0xffff0000u));
    unsigned l1 = pk_bf(a.z - __uint_as_float(h1 << 16),
                        a.w - __uint_as_float(h1 & 0xffff0000u));
    unsigned l2 = pk_bf(b.x - __uint_as_float(h2 << 16),
                        b.y - __uint_as_float(h2 & 0xffff0000u));
    unsigned l3 = pk_bf(b.z - __uint_as_float(h3 << 16),
                        b.w - __uint_as_float(h3 & 0xffff0000u));
    union U { unsigned u[4]; bf16x8 v; };
    U H; H.u[0] = h0; H.u[1] = h1; H.u[2] = h2; H.u[3] = h3; h = H.v;
    U L; L.u[0] = l0; L.u[1] = l1; L.u[2] = l2; L.u[3] = l3; l = L.v;
}

__device__ __forceinline__ int imin(int a, int b) { return a < b ? a : b; }

// ---------------------------------------------------------------------------
// setup: W1 -> k-chunked bf16 hi/lo; W2 -> transposed; zero degS (src degree
// table for the global-atomic out-degree histogram that replaces the whole
// src-side bucket machinery).
__global__ __launch_bounds__(256) void setup_cvt(
    const float* __restrict__ W1, const float* __restrict__ W2,
    unsigned short* __restrict__ W1ch, unsigned short* __restrict__ W1cl,
    unsigned short* __restrict__ W2th, unsigned short* __restrict__ W2tl,
    int* __restrict__ degS) {
    int i = blockIdx.x * 256 + threadIdx.x;
    if (i < IN_FEATS * N_HIDDEN) {
        int k = i >> 7, c = i & 127;
        float v = W1[i];
        unsigned short h = f2bf(v);
        int o = (k >> 5) * 4096 + c * 32 + (k & 31);
        W1ch[o] = h;
        W1cl[o] = f2bf(v - bf2f(h));
    } else if (i < IN_FEATS * N_HIDDEN + 48 * 128) {
        int j = i - IN_FEATS * N_HIDDEN;    // 0..6143
        int n = j >> 7, k = j & 127;
        float v = (n < N_CLASSES) ? W2[k * N_CLASSES + n] : 0.f;
        unsigned short h = f2bf(v);
        W2th[n * 128 + k] = h;
        W2tl[n * 128 + k] = f2bf(v - bf2f(h));
    } else {
        int j = i - (IN_FEATS * N_HIDDEN + 48 * 128);
        if (j < N_NODES) degS[j] = 0;
    }
}

// ---------------------------------------------------------------------------
// megaA: blocks [0,NBKT) = gemm1 tiles; blocks [NBKT,NBKT+NBLK) = p1_hist.
//
// gemm1 (r4 best variant, 62us): lane-linear LDS A-tiles (conflict-free) +
// register double-buffered B. hist: dst-bucket LDS histogram (for the
// ordered scatter) + DIRECT GLOBAL ATOMICS on degS for src out-degree —
// the src side needs only counts, not ordering, so the srcv/histS/scan-S
// machinery is deleted (r6 change).

#define MFJ(AH, AL, BH, BL, ACC)                                              \
    ACC = __builtin_amdgcn_mfma_f32_16x16x32_bf16(AH, BH, ACC, 0, 0, 0);      \
    ACC = __builtin_amdgcn_mfma_f32_16x16x32_bf16(AH, BL, ACC, 0, 0, 0);      \
    ACC = __builtin_amdgcn_mfma_f32_16x16x32_bf16(AL, BH, ACC, 0, 0, 0);

__global__ __launch_bounds__(256) void megaA(
    const int* __restrict__ src, const int* __restrict__ dst,
    int* __restrict__ histD, int* __restrict__ degS,
    const float* __restrict__ X, const unsigned short* __restrict__ Wch,
    const unsigned short* __restrict__ Wcl, unsigned short* __restrict__ Hb) {
    // LDS overlay: hist hd (3128B) vs gemm 2 x 8KB A-tile buffers (16KB).
    __shared__ __align__(16) unsigned char smem[16384];
    const int tid = threadIdx.x;

    if (blockIdx.x >= NBKT) {
        // ---- p1_hist: dst buckets in LDS, src degrees via global atomics ----
        int* hd = (int*)smem;
        int b = blockIdx.x - NBKT;
        for (int i = tid; i < NBKT; i += 256) hd[i] = 0;
        __syncthreads();
        int e0 = b * EPB;
        for (int i = tid; i < EPB; i += 256) {
            atomicAdd(&hd[dst[e0 + i] >> 6], 1);
            atomicAdd(&degS[src[e0 + i]], 1);
        }
        __syncthreads();
        for (int i = tid; i < NBKT; i += 256) histD[b * NBKT + i] = hd[i];
        return;
    }
    // ---- gemm1: 64 rows, split-precision bf16 MFMA, unscaled output ----
    typedef unsigned short ush;
    ush* lds = (ush*)smem;   // buf b at +b*4096 ush; h plane +0, l plane +2048

    const int lane = tid & 63;
    const int wv = tid >> 6;
    const int m = lane & 15;
    const int q = lane >> 4;
    const int q8 = q * 8;
    const int row0 = blockIdx.x * 64;

    const unsigned short* wbh = Wch + (wv * 32 + m) * 32 + q8;
    const unsigned short* wbl = Wcl + (wv * 32 + m) * 32 + q8;

    // staging assignment: thread t produces A-unit t
    const int srow = (tid >> 6) * 16 + (tid & 15);      // row within tile
    const int sq8  = ((tid >> 4) & 3) * 8;              // col group * 8
    const float* xp = &X[(size_t)imin(row0 + srow, N_NODES - 1) * IN_FEATS + sq8];

    f32x4 acc[4][2];
#pragma unroll
    for (int i = 0; i < 4; i++)
#pragma unroll
        for (int j = 0; j < 2; j++) acc[i][j] = (f32x4){0.f, 0.f, 0.f, 0.f};

    // prologue: chunk 0 -> buf0; X chunks 1,2 into registers; B chunk 0 regs
    {
        float4 p0 = *(const float4*)(xp);
        float4 p1 = *(const float4*)(xp + 4);
        bf16x8 h, l;
        cvt8(p0, p1, h, l);
        *(bf16x8*)(lds + tid * 8) = h;
        *(bf16x8*)(lds + 2048 + tid * 8) = l;
    }
    float4 a0 = *(const float4*)(xp + 32), a1 = *(const float4*)(xp + 36);
    float4 b0 = *(const float4*)(xp + 64), b1 = *(const float4*)(xp + 68);
    float4 n0 = a0, n1 = a1;
    bf16x8 cbh0 = *(const bf16x8*)(wbh);
    bf16x8 cbh1 = *(const bf16x8*)(wbh + 512);
    bf16x8 cbl0 = *(const bf16x8*)(wbl);
    bf16x8 cbl1 = *(const bf16x8*)(wbl + 512);
    __syncthreads();

    for (int kc = 0; kc < 16; kc++) {
        // issue NEXT chunk's B loads first — full chunk to cover L2 latency
        bf16x8 nbh0 = cbh0, nbh1 = cbh1, nbl0 = cbl0, nbl1 = cbl1;
        if (kc < 15) {
            nbh0 = *(const bf16x8*)(wbh + (kc + 1) * 4096);
            nbh1 = *(const bf16x8*)(wbh + (kc + 1) * 4096 + 512);
            nbl0 = *(const bf16x8*)(wbl + (kc + 1) * 4096);
            nbl1 = *(const bf16x8*)(wbl + (kc + 1) * 4096 + 512);
        }
        // deep X prefetch: chunk kc+3
        if (kc < 13) {
            n0 = *(const float4*)(xp + (kc + 3) * 32);
            n1 = *(const float4*)(xp + (kc + 3) * 32 + 4);
        }
        // stage chunk kc+1 into the other buffer (conv in MFMA shadow)
        if (kc < 15) {
            ush* bufw = lds + ((kc + 1) & 1) * 4096;
            bf16x8 h, l;
            cvt8(a0, a1, h, l);
            *(bf16x8*)(bufw + tid * 8) = h;
            *(bf16x8*)(bufw + 2048 + tid * 8) = l;
        }
        // fragment reads: lane-linear, conflict-free
        const ush* bufr = lds + (kc & 1) * 4096;
        bf16x8 ah0 = *(const bf16x8*)(bufr + (0 * 64 + lane) * 8);
        bf16x8 ah1 = *(const bf16x8*)(bufr + (1 * 64 + lane) * 8);
        bf16x8 ah2 = *(const bf16x8*)(bufr + (2 * 64 + lane) * 8);
        bf16x8 ah3 = *(const bf16x8*)(bufr + (3 * 64 + lane) * 8);
        bf16x8 al0 = *(const bf16x8*)(bufr + 2048 + (0 * 64 + lane) * 8);
        bf16x8 al1 = *(const bf16x8*)(bufr + 2048 + (1 * 64 + lane) * 8);
        bf16x8 al2 = *(const bf16x8*)(bufr + 2048 + (2 * 64 + lane) * 8);
        bf16x8 al3 = *(const bf16x8*)(bufr + 2048 + (3 * 64 + lane) * 8);

        MFJ(ah0, al0, cbh0, cbl0, acc[0][0]) MFJ(ah0, al0, cbh1, cbl1, acc[0][1])
        MFJ(ah1, al1, cbh0, cbl0, acc[1][0]) MFJ(ah1, al1, cbh1, cbl1, acc[1][1])
        MFJ(ah2, al2, cbh0, cbl0, acc[2][0]) MFJ(ah2, al2, cbh1, cbl1, acc[2][1])
        MFJ(ah3, al3, cbh0, cbl0, acc[3][0]) MFJ(ah3, al3, cbh1, cbl1, acc[3][1])

        if (kc < 15) __syncthreads();
        a0 = b0; a1 = b1; b0 = n0; b1 = n1;
        cbh0 = nbh0; cbh1 = nbh1; cbl0 = nbl0; cbl1 = nbl1;
    }

#pragma unroll
    for (int i = 0; i < 4; i++) {
#pragma unroll
        for (int r = 0; r < 4; r++) {
            int grow = row0 + i * 16 + q * 4 + r;
            if (grow < N_NODES) {
#pragma unroll
                for (int j = 0; j < 2; j++)
                    Hb[(size_t)grow * N_HIDDEN + wv * 32 + j * 16 + m] = f2bf(acc[i][j][r]);
            }
        }
    }
}

// ---------------------------------------------------------------------------
// P2a: one wave per bucket — parallel scan over the 800-block dimension
// (dst side only; src side now handled by degS atomics).
__global__ __launch_bounds__(256) void p2_local(
    const int* __restrict__ histD,
    int* __restrict__ baseD, int* __restrict__ totD) {
    int wv = threadIdx.x >> 6, lane = threadIdx.x & 63;
    int w = blockIdx.x * 4 + wv;
    if (w >= NBKT) return;
    int runD = 0;
#pragma unroll
    for (int c = 0; c < 13; c++) {
        int blk = c * 64 + lane;
        int vD = 0;
        if (blk < NBLK) vD = histD[blk * NBKT + w];
        int iD = vD;
#pragma unroll
        for (int off = 1; off < 64; off <<= 1) {
            int tD = __shfl_up(iD, off);
            if (lane >= off) iD += tD;
        }
        if (blk < NBLK) baseD[blk * NBKT + w] = runD + iD - vD;
        runD += __shfl(iD, 63);
    }
    if (lane == 0) totD[w] = runD;
}

// P2b: single-block scan over the 782 bucket totals (dst only).
__global__ __launch_bounds__(1024) void p2_small(
    const int* __restrict__ totD,
    int* __restrict__ bucket_base, int* __restrict__ offsets) {
    __shared__ int part[1024];
    int t = threadIdx.x;
    int v = (t < NBKT) ? totD[t] : 0;
    part[t] = v;
    __syncthreads();
    for (int off = 1; off < 1024; off <<= 1) {
        int x = (t >= off) ? part[t - off] : 0;
        __syncthreads();
        part[t] += x;
        __syncthreads();
    }
    if (t < NBKT) bucket_base[t] = part[t] - v;
    if (t == 0) { bucket_base[NBKT] = N_EDGES; offsets[N_NODES] = N_EDGES; }
}

// ---------------------------------------------------------------------------
// P3: scatter edges into dst-bucket-partitioned edata via LDS cursors.
__global__ __launch_bounds__(256) void p3_scatter(
    const int* __restrict__ src, const int* __restrict__ dst,
    const int* __restrict__ baseD, const int* __restrict__ bucket_base,
    unsigned int* __restrict__ edata) {
    __shared__ int curD[NBKT];
    int t = threadIdx.x, b = blockIdx.x;
    for (int i = t; i < NBKT; i += 256)
        curD[i] = bucket_base[i] + baseD[b * NBKT + i];
    __syncthreads();
    int e0 = b * EPB;
    for (int i = t; i < EPB; i += 256) {
        int s = src[e0 + i], d = dst[e0 + i];
        int slotD = atomicAdd(&curD[d >> 6], 1);
        edata[slotD] = (unsigned)s | ((unsigned)(d & 63) << 16);
    }
}

// ---------------------------------------------------------------------------
// P4 fused: dst-side count+scatter -> offsets, norm_dst, sorted_src;
// norm_src directly from degS. One block per bucket.
__global__ __launch_bounds__(256) void p4_fused(
    const int* __restrict__ degS,
    const int* __restrict__ bucket_base, const unsigned int* __restrict__ edata,
    int* __restrict__ offsets, float* __restrict__ norm_src,
    float* __restrict__ norm_dst, int* __restrict__ sorted_src) {
    __shared__ int cntD[64], cur[64];
    int t = threadIdx.x, b = blockIdx.x;
    if (t < 64) cntD[t] = 0;
    __syncthreads();
    int d0 = bucket_base[b], d1 = bucket_base[b + 1];
    for (int i = d0 + t; i < d1; i += 256)
        atomicAdd(&cntD[(edata[i] >> 16) & 63], 1);
    __syncthreads();
    if (t == 0) {
        int run = 0;
        for (int i = 0; i < 64; i++) { cur[i] = run; run += cntD[i]; }
    }
    __syncthreads();
    if (t < 64) {
        int node = b * 64 + t;
        if (node < N_NODES) {
            norm_src[node] = rsqrtf(fmaxf((float)degS[node], 1.0f));
            offsets[node] = d0 + cur[t];
            norm_dst[node] = rsqrtf(fmaxf((float)cntD[t], 1.0f));
        }
    }
    __syncthreads();
    for (int i = d0 + t; i < d1; i += 256) {
        unsigned e = edata[i];
        int slot = atomicAdd(&cur[(e >> 16) & 63], 1);
        sorted_src[d0 + slot] = (int)(e & 0xFFFFu);
    }
}

// ---------------------------------------------------------------------------
// agg1: one wave per dst node; per-edge norm_src fma (Hb is unscaled),
// 16 edges in flight (4 b128/lane), xor-16/32 butterfly, fused
// norm_dst+bias+relu, H1 out bf16 hi/lo with norm_src[wid] folded (for gemm2).
#define FMA8(W, NS)                                                   \
    acc0 = fmaf(__uint_as_float((W).x << 16), NS, acc0);              \
    acc1 = fmaf(__uint_as_float((W).x & 0xffff0000u), NS, acc1);      \
    acc2 = fmaf(__uint_as_float((W).y << 16), NS, acc2);              \
    acc3 = fmaf(__uint_as_float((W).y & 0xffff0000u), NS, acc3);      \
    acc4 = fmaf(__uint_as_float((W).z << 16), NS, acc4);              \
    acc5 = fmaf(__uint_as_float((W).z & 0xffff0000u), NS, acc5);      \
    acc6 = fmaf(__uint_as_float((W).w << 16), NS, acc6);              \
    acc7 = fmaf(__uint_as_float((W).w & 0xffff0000u), NS, acc7);

__global__ __launch_bounds__(256) void agg1_kernel(
    const int* __restrict__ offsets, const int* __restrict__ sorted_src,
    const unsigned short* __restrict__ Hb, const float* __restrict__ norm_dst,
    const float* __restrict__ norm_src, const float* __restrict__ b1,
    unsigned short* __restrict__ H1h, unsigned short* __restrict__ H1l) {
    int wid = (blockIdx.x * 256 + threadIdx.x) >> 6;
    int lane = threadIdx.x & 63;
    if (wid >= N_NODES) return;
    int start = offsets[wid], end = offsets[wid + 1];
    int quad = lane >> 4;
    int c8 = (lane & 15) * 8;
    float acc0 = 0.f, acc1 = 0.f, acc2 = 0.f, acc3 = 0.f;
    float acc4 = 0.f, acc5 = 0.f, acc6 = 0.f, acc7 = 0.f;
    int base = start;
    for (; base + 16 <= end; base += 16) {
        int e0 = sorted_src[base + quad];
        int e1 = sorted_src[base + 4 + quad];
        int e2 = sorted_src[base + 8 + quad];
        int e3 = sorted_src[base + 12 + quad];
        float n0 = norm_src[e0], n1 = norm_src[e1];
        float n2 = norm_src[e2], n3 = norm_src[e3];
        uint4 w0 = *(const uint4*)&Hb[(size_t)e0 * N_HIDDEN + c8];
        uint4 w1 = *(const uint4*)&Hb[(size_t)e1 * N_HIDDEN + c8];
        uint4 w2 = *(const uint4*)&Hb[(size_t)e2 * N_HIDDEN + c8];
        uint4 w3 = *(const uint4*)&Hb[(size_t)e3 * N_HIDDEN + c8];
        FMA8(w0, n0);
        FMA8(w1, n1);
        FMA8(w2, n2);
        FMA8(w3, n3);
    }
    for (; base + 4 <= end; base += 4) {
        int e = sorted_src[base + quad];
        float n = norm_src[e];
        uint4 w = *(const uint4*)&Hb[(size_t)e * N_HIDDEN + c8];
        FMA8(w, n);
    }
    int rem = end - base;
    if (quad < rem) {
        int e = sorted_src[base + quad];
        float n = norm_src[e];
        uint4 w = *(const uint4*)&Hb[(size_t)e * N_HIDDEN + c8];
        FMA8(w, n);
    }
    acc0 += __shfl_xor(acc0, 16); acc0 += __shfl_xor(acc0, 32);
    acc1 += __shfl_xor(acc1, 16); acc1 += __shfl_xor(acc1, 32);
    acc2 += __shfl_xor(acc2, 16); acc2 += __shfl_xor(acc2, 32);
    acc3 += __shfl_xor(acc3, 16); acc3 += __shfl_xor(acc3, 32);
    acc4 += __shfl_xor(acc4, 16); acc4 += __shfl_xor(acc4, 32);
    acc5 += __shfl_xor(acc5, 16); acc5 += __shfl_xor(acc5, 32);
    acc6 += __shfl_xor(acc6, 16); acc6 += __shfl_xor(acc6, 32);
    acc7 += __shfl_xor(acc7, 16); acc7 += __shfl_xor(acc7, 32);
    if (quad == 0) {
        float nd = norm_dst[wid];
        float ns = norm_src[wid];
        float4 ba = *(const float4*)&b1[c8];
        float4 bb = *(const float4*)&b1[c8 + 4];
        float o[8];
        o[0] = fmaxf(acc0 * nd + ba.x, 0.f) * ns;
        o[1] = fmaxf(acc1 * nd + ba.y, 0.f) * ns;
        o[2] = fmaxf(acc2 * nd + ba.z, 0.f) * ns;
        o[3] = fmaxf(acc3 * nd + ba.w, 0.f) * ns;
        o[4] = fmaxf(acc4 * nd + bb.x, 0.f) * ns;
        o[5] = fmaxf(acc5 * nd + bb.y, 0.f) * ns;
        o[6] = fmaxf(acc6 * nd + bb.z, 0.f) * ns;
        o[7] = fmaxf(acc7 * nd + bb.w, 0.f) * ns;
        unsigned short hh[8], ll[8];
#pragma unroll
        for (int t = 0; t < 8; t++) {
            hh[t] = f2bf(o[t]);
            ll[t] = f2bf(o[t] - bf2f(hh[t]));
        }
        uint4 ph = make_uint4((unsigned)hh[0] | ((unsigned)hh[1] << 16),
                              (unsigned)hh[2] | ((unsigned)hh[3] << 16),
                              (unsigned)hh[4] | ((unsigned)hh[5] << 16),
                              (unsigned)hh[6] | ((unsigned)hh[7] << 16));
        uint4 pl = make_uint4((unsigned)ll[0] | ((unsigned)ll[1] << 16),
                              (unsigned)ll[2] | ((unsigned)ll[3] << 16),
                              (unsigned)ll[4] | ((unsigned)ll[5] << 16),
                              (unsigned)ll[6] | ((unsigned)ll[7] << 16));
        *(uint4*)&H1h[(size_t)wid * N_HIDDEN + c8] = ph;
        *(uint4*)&H1l[(size_t)wid * N_HIDDEN + c8] = pl;
    }
}

// ---------------------------------------------------------------------------
// GEMM2 via bf16 MFMA: H2u[n][0:40] = H1n @ W2, PACKED hi|lo bf16 in u32
// (full f32 precision to 2^-17 rel), 48-dword rows for 16B-aligned gathers.
__global__ __launch_bounds__(256) void gemm2_kernel(
    const unsigned short* __restrict__ H1h, const unsigned short* __restrict__ H1l,
    const unsigned short* __restrict__ W2th, const unsigned short* __restrict__ W2tl,
    unsigned int* __restrict__ H2u) {
    __shared__ __align__(16) unsigned short Bh[48][136];
    __shared__ __align__(16) unsigned short Bl[48][136];
    const int tid = threadIdx.x;
    for (int i = tid; i < 48 * 16; i += 256) {
        int n = i >> 4, kq = (i & 15) * 8;
        *(uint4*)&Bh[n][kq] = *(const uint4*)&W2th[n * 128 + kq];
        *(uint4*)&Bl[n][kq] = *(const uint4*)&W2tl[n * 128 + kq];
    }
    __syncthreads();
    const int lane = tid & 63;
    const int wave = tid >> 6;
    const int m = lane & 15;
    const int q = lane >> 4;
    const int row0 = blockIdx.x * 128 + wave * 32;

    f32x4 acc[2][3];
#pragma unroll
    for (int i = 0; i < 2; i++)
#pragma unroll
        for (int j = 0; j < 3; j++) acc[i][j] = (f32x4){0.f, 0.f, 0.f, 0.f};

#pragma unroll
    for (int kc = 0; kc < 4; kc++) {
        bf16x8 bh[3], bl[3];
#pragma unroll
        for (int j = 0; j < 3; j++) {
            bh[j] = *(const bf16x8*)&Bh[j * 16 + m][kc * 32 + q * 8];
            bl[j] = *(const bf16x8*)&Bl[j * 16 + m][kc * 32 + q * 8];
        }
#pragma unroll
        for (int i = 0; i < 2; i++) {
            size_t ro = (size_t)(row0 + i * 16 + m) * N_HIDDEN + kc * 32 + q * 8;
            bf16x8 ah = *(const bf16x8*)&H1h[ro];
            bf16x8 al = *(const bf16x8*)&H1l[ro];
#pragma unroll
            for (int j = 0; j < 3; j++) {
                acc[i][j] = __builtin_amdgcn_mfma_f32_16x16x32_bf16(ah, bh[j], acc[i][j], 0, 0, 0);
                acc[i][j] = __builtin_amdgcn_mfma_f32_16x16x32_bf16(ah, bl[j], acc[i][j], 0, 0, 0);
                acc[i][j] = __builtin_amdgcn_mfma_f32_16x16x32_bf16(al, bh[j], acc[i][j], 0, 0, 0);
            }
        }
    }
#pragma unroll
    for (int i = 0; i < 2; i++) {
#pragma unroll
        for (int r = 0; r < 4; r++) {
            int row = row0 + i * 16 + q * 4 + r;
            if (row < N_NODES) {
#pragma unroll
                for (int j = 0; j < 3; j++) {
                    int col = j * 16 + m;
                    if (col < N_CLASSES) {
                        float v = acc[i][j][r];
                        unsigned short h = f2bf(v);
                        unsigned short l = f2bf(v - bf2f(h));
                        H2u[(size_t)row * 48 + col] = ((unsigned)h << 16) | (unsigned)l;
                    }
                }
            }
        }
    }
}

// ---------------------------------------------------------------------------
// agg2: one wave per dst node; 16 edges in flight (4 uint4/lane), packed
// hi|lo bf16 reconstruction, butterfly reduce.
#define ACC4(V)                                                               \
    acc.x += __uint_as_float((V).x & 0xffff0000u) + __uint_as_float((V).x << 16); \
    acc.y += __uint_as_float((V).y & 0xffff0000u) + __uint_as_float((V).y << 16); \
    acc.z += __uint_as_float((V).z & 0xffff0000u) + __uint_as_float((V).z << 16); \
    acc.w += __uint_as_float((V).w & 0xffff0000u) + __uint_as_float((V).w << 16);

__global__ __launch_bounds__(256) void agg2_kernel(
    const int* __restrict__ offsets, const int* __restrict__ sorted_src,
    const unsigned int* __restrict__ H2u, const float* __restrict__ norm_dst,
    const float* __restrict__ b2, float* __restrict__ OUT) {
    int wid = (blockIdx.x * 256 + threadIdx.x) >> 6;
    int lane = threadIdx.x & 63;
    if (wid >= N_NODES) return;
    int start = offsets[wid], end = offsets[wid + 1];
    int quad = lane >> 4;
    int c4 = (lane & 15) * 4;
    bool active = c4 < N_CLASSES;
    float4 acc = make_float4(0.f, 0.f, 0.f, 0.f);
    int base = start;
    for (; base + 16 <= end; base += 16) {
        int e0 = sorted_src[base + quad];
        int e1 = sorted_src[base + 4 + quad];
        int e2 = sorted_src[base + 8 + quad];
        int e3 = sorted_src[base + 12 + quad];
        if (active) {
            uint4 v0 = *(const uint4*)&H2u[(size_t)e0 * 48 + c4];
            uint4 v1 = *(const uint4*)&H2u[(size_t)e1 * 48 + c4];
            uint4 v2 = *(const uint4*)&H2u[(size_t)e2 * 48 + c4];
            uint4 v3 = *(const uint4*)&H2u[(size_t)e3 * 48 + c4];
            ACC4(v0); ACC4(v1); ACC4(v2); ACC4(v3);
        }
    }
    for (; base + 4 <= end; base += 4) {
        int e = sorted_src[base + quad];
        if (active) {
            uint4 v = *(const uint4*)&H2u[(size_t)e * 48 + c4];
            ACC4(v);
        }
    }
    int rem = end - base;
    if (quad < rem && active) {
        int e = sorted_src[base + quad];
        uint4 v = *(const uint4*)&H2u[(size_t)e * 48 + c4];
        ACC4(v);
    }
    acc.x += __shfl_xor(acc.x, 16); acc.x += __shfl_xor(acc.x, 32);
    acc.y += __shfl_xor(acc.y, 16); acc.y += __shfl_xor(acc.y, 32);
    acc.z += __shfl_xor(acc.z, 16); acc.z += __shfl_xor(acc.z, 32);
    acc.w += __shfl_xor(acc.w, 16); acc.w += __shfl_xor(acc.w, 32);
    if (lane < 10) {
        float nd = norm_dst[wid];
        float4 b = *(const float4*)&b2[lane * 4];
        acc.x = acc.x * nd + b.x;
        acc.y = acc.y * nd + b.y;
        acc.z = acc.z * nd + b.z;
        acc.w = acc.w * nd + b.w;
        *(float4*)&OUT[(size_t)wid * N_CLASSES + lane * 4] = acc;
    }
}

// ---------------------------------------------------------------------------
extern "C" void kernel_launch(void* const* d_in, const int* in_sizes, int n_in,
                              void* d_out, int out_size, void* d_ws, size_t ws_size,
                              hipStream_t stream) {
    const float* X   = (const float*)d_in[0];
    const float* W1  = (const float*)d_in[1];
    const float* b1  = (const float*)d_in[2];
    const float* W2  = (const float*)d_in[3];
    const float* b2  = (const float*)d_in[4];
    const int*   src = (const int*)d_in[5];
    const int*   dst = (const int*)d_in[6];
    float* out = (float*)d_out;

    // workspace layout (4B units). regionA time-shared:
    //   phase 1: histD|baseD|totD                      [dead after p3]
    //   phase 3: H2u packed u32 50000x48 (2.4M dwords) [written at gemm2]
    // Hb has its own region (written by megaA while phase-1 data live).
    float* norm_src   = (float*)d_ws;                     // 50000
    float* norm_dst   = norm_src + N_NODES;               // 50000
    int*   offsets    = (int*)(norm_dst + N_NODES);       // 50016 (incl pad)
    int*   bucket_base = offsets + N_NODES + 16;          // 800
    int*   spare      = bucket_base + 800;                // 800 (unused)
    unsigned int* edata = (unsigned int*)(spare + 800);           // 1.6M
    int*   degS       = (int*)(edata + N_EDGES);          // 50000 (was srcv)
    int*   sorted_src = (int*)(edata + N_EDGES) + 400000; // 1.6M
    int*   regionA    = sorted_src + N_EDGES;             // 3.2M dwords
    int*   histD      = regionA;
    int*   baseD      = regionA + 625600;
    int*   totD       = regionA + 1251200;                // 800
    unsigned int* H2u = (unsigned int*)regionA;           // phase 3 (2.4M)
    unsigned short* H1h = (unsigned short*)(regionA + 3200000);   // 50048x128 bf16
    unsigned short* H1l = H1h + (size_t)NROWPAD * N_HIDDEN;
    unsigned short* W1ch = H1l + (size_t)NROWPAD * N_HIDDEN;      // k-chunked 512*128
    unsigned short* W1cl = W1ch + IN_FEATS * N_HIDDEN;
    unsigned short* W2th = W1cl + IN_FEATS * N_HIDDEN;            // 48*128
    unsigned short* W2tl = W2th + 48 * 128;
    unsigned short* Hb   = W2tl + 48 * 128;               // 50000x128 bf16 (own region)

    // setup grid covers W1 (65536) + W2t (6144) + degS zeroing (50000)
    setup_cvt<<<(IN_FEATS * N_HIDDEN + 48 * 128 + N_NODES + 255) / 256, 256, 0, stream>>>(
        W1, W2, W1ch, W1cl, W2th, W2tl, degS);
    megaA<<<NBLK + NBKT, 256, 0, stream>>>(src, dst, histD, degS, X, W1ch, W1cl, Hb);
    p2_local<<<(NBKT + 3) / 4, 256, 0, stream>>>(histD, baseD, totD);
    p2_small<<<1, 1024, 0, stream>>>(totD, bucket_base, offsets);
    p3_scatter<<<NBLK, 256, 0, stream>>>(src, dst, baseD, bucket_base, edata);
    p4_fused<<<NBKT, 256, 0, stream>>>(degS, bucket_base, edata,
                                       offsets, norm_src, norm_dst, sorted_src);
    agg1_kernel<<<(N_NODES + 3) / 4, 256, 0, stream>>>(offsets, sorted_src, Hb, norm_dst,
                                                       norm_src, b1, H1h, H1l);
    gemm2_kernel<<<(N_NODES + 127) / 128, 256, 0, stream>>>(H1h, H1l, W2th, W2tl, H2u);
    agg2_kernel<<<(N_NODES + 3) / 4, 256, 0, stream>>>(offsets, sorted_src, H2u, norm_dst, b2, out);
}

// Round 7
// 357.079 us; speedup vs baseline: 1.0870x; 1.0590x over previous
//
#include <hip/hip_runtime.h>
#include <hip/hip_bf16.h>

#define N_NODES 50000
#define N_EDGES 1600000
#define IN_FEATS 512
#define N_HIDDEN 128
#define N_CLASSES 40
#define NBKT 782      // ceil(50000/64) buckets of 64 nodes
#define NBLK 800      // partition blocks
#define EPB 2000      // edges per partition block (800*2000 = 1.6M exact)
#define NROWPAD 50048 // 391*128, padded row count for gemm2 A-reads

typedef __attribute__((ext_vector_type(8))) short bf16x8;
typedef __attribute__((ext_vector_type(4))) float f32x4;

__device__ __forceinline__ unsigned short f2bf(float f) {
    unsigned u = __float_as_uint(f);
    u = (u + 0x7FFFu + ((u >> 16) & 1u)) >> 16;   // round-to-nearest-even
    return (unsigned short)u;
}
__device__ __forceinline__ float bf2f(unsigned short h) {
    return __uint_as_float(((unsigned)h) << 16);
}
// packed f32x2 -> bf16x2 (RTNE), lowers to v_cvt_pk_bf16_f32 on gfx950
__device__ __forceinline__ unsigned pk_bf(float a, float b) {
    __hip_bfloat162 h = __float22bfloat162_rn(make_float2(a, b));
    union { __hip_bfloat162 v; unsigned u; } c;
    c.v = h;
    return c.u;   // low 16 = bf(a), high 16 = bf(b)
}

// 8 floats (two float4) -> hi/lo bf16x8 fragments, in registers.
__device__ __forceinline__ void cvt8(float4 a, float4 b, bf16x8& h, bf16x8& l) {
    unsigned h0 = pk_bf(a.x, a.y), h1 = pk_bf(a.z, a.w);
    unsigned h2 = pk_bf(b.x, b.y), h3 = pk_bf(b.z, b.w);
    unsigned l0 = pk_bf(a.x - __uint_as_float(h0 << 16),
                        a.y - __uint_as_float(h0 & 0xffff0000u));
    unsigned l1 = pk_bf(a.z - __uint_as_float(h1 << 16),
                        a.w - __uint_as_float(h1 & 0xffff0000u));
    unsigned l2 = pk_bf(b.x - __uint_as_float(h2 << 16),
                        b.y - __uint_as_float(h2 & 0xffff0000u));
    unsigned l3 = pk_bf(b.z - __uint_as_float(h3 << 16),
                        b.w - __uint_as_float(h3 & 0xffff0000u));
    union U { unsigned u[4]; bf16x8 v; };
    U H; H.u[0] = h0; H.u[1] = h1; H.u[2] = h2; H.u[3] = h3; h = H.v;
    U L; L.u[0] = l0; L.u[1] = l1; L.u[2] = l2; L.u[3] = l3; l = L.v;
}

__device__ __forceinline__ int imin(int a, int b) { return a < b ? a : b; }

// ---------------------------------------------------------------------------
// setup: W1 -> k-chunked bf16 hi/lo [kc][col][ki]; W2 -> transposed [48][128]
__global__ __launch_bounds__(256) void setup_cvt(
    const float* __restrict__ W1, const float* __restrict__ W2,
    unsigned short* __restrict__ W1ch, unsigned short* __restrict__ W1cl,
    unsigned short* __restrict__ W2th, unsigned short* __restrict__ W2tl) {
    int i = blockIdx.x * 256 + threadIdx.x;
    if (i < IN_FEATS * N_HIDDEN) {
        int k = i >> 7, c = i & 127;
        float v = W1[i];
        unsigned short h = f2bf(v);
        int o = (k >> 5) * 4096 + c * 32 + (k & 31);
        W1ch[o] = h;
        W1cl[o] = f2bf(v - bf2f(h));
    } else {
        int j = i - IN_FEATS * N_HIDDEN;    // 0..6143 (grid sized exactly)
        int n = j >> 7, k = j & 127;
        float v = (n < N_CLASSES) ? W2[k * N_CLASSES + n] : 0.f;
        unsigned short h = f2bf(v);
        W2th[n * 128 + k] = h;
        W2tl[n * 128 + k] = f2bf(v - bf2f(h));
    }
}

// ---------------------------------------------------------------------------
// megaA: blocks [0,NBKT) = gemm1 tiles; blocks [NBKT,NBKT+NBLK) = p1_hist.
//
// gemm1 r7: lane-linear LDS (conflict-free, r3-verified) with TWO CHUNKS PER
// BARRIER. r6's Little's-law analysis: the per-chunk __syncthreads drains
// vmcnt(0) every 8KB staged -> in-flight bytes cap X stream at ~1.2 TB/s.
// 4 LDS buffers (32KB): stage pair p+1 (16KB) while computing pair p,
// ONE barrier per pair -> 8 barriers instead of 16, 2x bytes per drain.
// Staging writes and fragment reads both remain wave-contiguous (zero gemm
// bank conflicts). B reg-dbuf dropped (r4 measured neutral).

#define MFJ(AH, AL, BH, BL, ACC)                                              \
    ACC = __builtin_amdgcn_mfma_f32_16x16x32_bf16(AH, BH, ACC, 0, 0, 0);      \
    ACC = __builtin_amdgcn_mfma_f32_16x16x32_bf16(AH, BL, ACC, 0, 0, 0);      \
    ACC = __builtin_amdgcn_mfma_f32_16x16x32_bf16(AL, BH, ACC, 0, 0, 0);

#define CHUNK_COMPUTE(FRAGBASE, KC)                                           \
    {                                                                         \
        const unsigned short* wk  = wbh + (KC) * 4096;                        \
        const unsigned short* wkl = wbl + (KC) * 4096;                        \
        bf16x8 bh0 = *(const bf16x8*)(wk);                                    \
        bf16x8 bh1 = *(const bf16x8*)(wk + 512);                              \
        bf16x8 bl0 = *(const bf16x8*)(wkl);                                   \
        bf16x8 bl1 = *(const bf16x8*)(wkl + 512);                             \
        const unsigned short* fb = (FRAGBASE);                                \
        bf16x8 ah0 = *(const bf16x8*)(fb + (0 * 64 + lane) * 8);              \
        bf16x8 ah1 = *(const bf16x8*)(fb + (1 * 64 + lane) * 8);              \
        bf16x8 ah2 = *(const bf16x8*)(fb + (2 * 64 + lane) * 8);              \
        bf16x8 ah3 = *(const bf16x8*)(fb + (3 * 64 + lane) * 8);              \
        bf16x8 al0 = *(const bf16x8*)(fb + 2048 + (0 * 64 + lane) * 8);       \
        bf16x8 al1 = *(const bf16x8*)(fb + 2048 + (1 * 64 + lane) * 8);       \
        bf16x8 al2 = *(const bf16x8*)(fb + 2048 + (2 * 64 + lane) * 8);       \
        bf16x8 al3 = *(const bf16x8*)(fb + 2048 + (3 * 64 + lane) * 8);       \
        MFJ(ah0, al0, bh0, bl0, acc[0][0]) MFJ(ah0, al0, bh1, bl1, acc[0][1]) \
        MFJ(ah1, al1, bh0, bl0, acc[1][0]) MFJ(ah1, al1, bh1, bl1, acc[1][1]) \
        MFJ(ah2, al2, bh0, bl0, acc[2][0]) MFJ(ah2, al2, bh1, bl1, acc[2][1]) \
        MFJ(ah3, al3, bh0, bl0, acc[3][0]) MFJ(ah3, al3, bh1, bl1, acc[3][1]) \
    }

__global__ __launch_bounds__(256) void megaA(
    const int* __restrict__ src, const int* __restrict__ dst,
    int* __restrict__ histD, int* __restrict__ histS,
    const float* __restrict__ X, const unsigned short* __restrict__ Wch,
    const unsigned short* __restrict__ Wcl, unsigned short* __restrict__ Hb) {
    // LDS overlay: hist hd/hs (6256B) vs gemm 2 sets x 16KB (pair of chunk
    // buffers, each chunk: hi 4KB + lo 4KB).
    __shared__ __align__(16) unsigned char smem[32768];
    const int tid = threadIdx.x;

    if (blockIdx.x >= NBKT) {
        // ---- p1_hist ----
        int* hd = (int*)smem;
        int* hs = hd + NBKT;
        int b = blockIdx.x - NBKT;
        for (int i = tid; i < NBKT; i += 256) { hd[i] = 0; hs[i] = 0; }
        __syncthreads();
        int e0 = b * EPB;
        for (int i = tid; i < EPB; i += 256) {
            atomicAdd(&hd[dst[e0 + i] >> 6], 1);
            atomicAdd(&hs[src[e0 + i] >> 6], 1);
        }
        __syncthreads();
        for (int i = tid; i < NBKT; i += 256) {
            histD[b * NBKT + i] = hd[i];
            histS[b * NBKT + i] = hs[i];
        }
        return;
    }
    // ---- gemm1: 64 rows, split-precision bf16 MFMA, unscaled output ----
    typedef unsigned short ush;
    ush* lds = (ush*)smem;   // set s at + s*8192 ush; within set:
                             // chunkA hi +0, lo +2048; chunkB hi +4096, lo +6144

    const int lane = tid & 63;
    const int wv = tid >> 6;
    const int m = lane & 15;
    const int q = lane >> 4;
    const int q8 = q * 8;
    const int row0 = blockIdx.x * 64;

    const unsigned short* wbh = Wch + (wv * 32 + m) * 32 + q8;
    const unsigned short* wbl = Wcl + (wv * 32 + m) * 32 + q8;

    // staging assignment: thread t produces A-unit t of each chunk
    const int srow = (tid >> 6) * 16 + (tid & 15);      // row within tile
    const int sq8  = ((tid >> 4) & 3) * 8;              // col group * 8
    const float* xp = &X[(size_t)imin(row0 + srow, N_NODES - 1) * IN_FEATS + sq8];

    f32x4 acc[4][2];
#pragma unroll
    for (int i = 0; i < 4; i++)
#pragma unroll
        for (int j = 0; j < 2; j++) acc[i][j] = (f32x4){0.f, 0.f, 0.f, 0.f};

    // prologue: stage pair 0 (chunks 0,1) into set 0; pair 1 X into regs
    {
        float4 c00 = *(const float4*)(xp),      c01 = *(const float4*)(xp + 4);
        float4 c10 = *(const float4*)(xp + 32), c11 = *(const float4*)(xp + 36);
        bf16x8 h, l;
        cvt8(c00, c01, h, l);
        *(bf16x8*)(lds + tid * 8) = h;
        *(bf16x8*)(lds + 2048 + tid * 8) = l;
        cvt8(c10, c11, h, l);
        *(bf16x8*)(lds + 4096 + tid * 8) = h;
        *(bf16x8*)(lds + 6144 + tid * 8) = l;
    }
    float4 a00 = *(const float4*)(xp + 64), a01 = *(const float4*)(xp + 68);
    float4 a10 = *(const float4*)(xp + 96), a11 = *(const float4*)(xp + 100);
    __syncthreads();

    for (int pp = 0; pp < 8; pp++) {
        // stage pair pp+1 into the other set (from regs; conv in MFMA shadow)
        if (pp < 7) {
            ush* bs = lds + ((pp + 1) & 1) * 8192;
            bf16x8 h, l;
            cvt8(a00, a01, h, l);
            *(bf16x8*)(bs + tid * 8) = h;
            *(bf16x8*)(bs + 2048 + tid * 8) = l;
            cvt8(a10, a11, h, l);
            *(bf16x8*)(bs + 4096 + tid * 8) = h;
            *(bf16x8*)(bs + 6144 + tid * 8) = l;
        }
        // prefetch pair pp+2 X into regs (2 barrier-intervals to resolve)
        if (pp < 6) {
            const float* xq = xp + (pp + 2) * 64;
            a00 = *(const float4*)(xq);      a01 = *(const float4*)(xq + 4);
            a10 = *(const float4*)(xq + 32); a11 = *(const float4*)(xq + 36);
        }
        // compute both chunks of pair pp
        const ush* br = lds + (pp & 1) * 8192;
        CHUNK_COMPUTE(br,        2 * pp)
        CHUNK_COMPUTE(br + 4096, 2 * pp + 1)
        if (pp < 7) __syncthreads();
    }

#pragma unroll
    for (int i = 0; i < 4; i++) {
#pragma unroll
        for (int r = 0; r < 4; r++) {
            int grow = row0 + i * 16 + q * 4 + r;
            if (grow < N_NODES) {
#pragma unroll
                for (int j = 0; j < 2; j++)
                    Hb[(size_t)grow * N_HIDDEN + wv * 32 + j * 16 + m] = f2bf(acc[i][j][r]);
            }
        }
    }
}

// ---------------------------------------------------------------------------
// P2a: one wave per bucket — parallel scan over the 800-block dimension.
__global__ __launch_bounds__(256) void p2_local(
    const int* __restrict__ histD, const int* __restrict__ histS,
    int* __restrict__ baseD, int* __restrict__ baseS,
    int* __restrict__ totD, int* __restrict__ totS) {
    int wv = threadIdx.x >> 6, lane = threadIdx.x & 63;
    int w = blockIdx.x * 4 + wv;
    if (w >= NBKT) return;
    int runD = 0, runS = 0;
#pragma unroll
    for (int c = 0; c < 13; c++) {
        int blk = c * 64 + lane;
        int vD = 0, vS = 0;
        if (blk < NBLK) {
            vD = histD[blk * NBKT + w];
            vS = histS[blk * NBKT + w];
        }
        int iD = vD, iS = vS;
#pragma unroll
        for (int off = 1; off < 64; off <<= 1) {
            int tD = __shfl_up(iD, off);
            int tS = __shfl_up(iS, off);
            if (lane >= off) { iD += tD; iS += tS; }
        }
        if (blk < NBLK) {
            baseD[blk * NBKT + w] = runD + iD - vD;
            baseS[blk * NBKT + w] = runS + iS - vS;
        }
        runD += __shfl(iD, 63);
        runS += __shfl(iS, 63);
    }
    if (lane == 0) { totD[w] = runD; totS[w] = runS; }
}

// P2b: single-block scan over the 782 bucket totals only.
__global__ __launch_bounds__(1024) void p2_small(
    const int* __restrict__ totD, const int* __restrict__ totS,
    int* __restrict__ bucket_base, int* __restrict__ srcb_base,
    int* __restrict__ offsets) {
    __shared__ int part[1024];
    int t = threadIdx.x;
    int v = (t < NBKT) ? totD[t] : 0;
    part[t] = v;
    __syncthreads();
    for (int off = 1; off < 1024; off <<= 1) {
        int x = (t >= off) ? part[t - off] : 0;
        __syncthreads();
        part[t] += x;
        __syncthreads();
    }
    if (t < NBKT) bucket_base[t] = part[t] - v;
    if (t == 0) { bucket_base[NBKT] = N_EDGES; offsets[N_NODES] = N_EDGES; }
    __syncthreads();
    v = (t < NBKT) ? totS[t] : 0;
    part[t] = v;
    __syncthreads();
    for (int off = 1; off < 1024; off <<= 1) {
        int x = (t >= off) ? part[t - off] : 0;
        __syncthreads();
        part[t] += x;
        __syncthreads();
    }
    if (t < NBKT) srcb_base[t] = part[t] - v;
    if (t == 0) srcb_base[NBKT] = N_EDGES;
}

// ---------------------------------------------------------------------------
// P3: scatter edges into bucket-partitioned arrays via LDS cursors.
__global__ __launch_bounds__(256) void p3_scatter(
    const int* __restrict__ src, const int* __restrict__ dst,
    const int* __restrict__ baseD, const int* __restrict__ baseS,
    const int* __restrict__ bucket_base, const int* __restrict__ srcb_base,
    unsigned int* __restrict__ edata, unsigned char* __restrict__ srcv) {
    __shared__ int curD[NBKT], curS[NBKT];
    int t = threadIdx.x, b = blockIdx.x;
    for (int i = t; i < NBKT; i += 256) {
        curD[i] = bucket_base[i] + baseD[b * NBKT + i];
        curS[i] = srcb_base[i] + baseS[b * NBKT + i];
    }
    __syncthreads();
    int e0 = b * EPB;
    for (int i = t; i < EPB; i += 256) {
        int s = src[e0 + i], d = dst[e0 + i];
        int slotD = atomicAdd(&curD[d >> 6], 1);
        edata[slotD] = (unsigned)s | ((unsigned)(d & 63) << 16);
        int slotS = atomicAdd(&curS[s >> 6], 1);
        srcv[slotS] = (unsigned char)(s & 63);
    }
}

// ---------------------------------------------------------------------------
// P4 fused: src-side count -> norm_src; dst-side count+scatter -> offsets,
// norm_dst, sorted_src (ushort: node ids < 65536). One block per bucket.
__global__ __launch_bounds__(256) void p4_fused(
    const int* __restrict__ srcb_base, const unsigned char* __restrict__ srcv,
    const int* __restrict__ bucket_base, const unsigned int* __restrict__ edata,
    int* __restrict__ offsets, float* __restrict__ norm_src,
    float* __restrict__ norm_dst, unsigned short* __restrict__ sorted_src) {
    __shared__ int cntS[64], cntD[64], cur[64];
    int t = threadIdx.x, b = blockIdx.x;
    if (t < 64) { cntS[t] = 0; cntD[t] = 0; }
    __syncthreads();
    int s0 = srcb_base[b], s1 = srcb_base[b + 1];
    for (int i = s0 + t; i < s1; i += 256) atomicAdd(&cntS[srcv[i]], 1);
    int d0 = bucket_base[b], d1 = bucket_base[b + 1];
    for (int i = d0 + t; i < d1; i += 256)
        atomicAdd(&cntD[(edata[i] >> 16) & 63], 1);
    __syncthreads();
    if (t == 0) {
        int run = 0;
        for (int i = 0; i < 64; i++) { cur[i] = run; run += cntD[i]; }
    }
    __syncthreads();
    if (t < 64) {
        int node = b * 64 + t;
        if (node < N_NODES) {
            norm_src[node] = rsqrtf(fmaxf((float)cntS[t], 1.0f));
            offsets[node] = d0 + cur[t];
            norm_dst[node] = rsqrtf(fmaxf((float)cntD[t], 1.0f));
        }
    }
    __syncthreads();
    for (int i = d0 + t; i < d1; i += 256) {
        unsigned e = edata[i];
        int slot = atomicAdd(&cur[(e >> 16) & 63], 1);
        sorted_src[d0 + slot] = (unsigned short)(e & 0xFFFFu);
    }
}

// ---------------------------------------------------------------------------
// agg1: one wave per dst node; per-edge norm_src fma (Hb is unscaled),
// 16 edges in flight (4 b128/lane), xor-16/32 butterfly, fused
// norm_dst+bias+relu, H1 out bf16 hi/lo with norm_src[wid] folded (for gemm2).
#define FMA8(W, NS)                                                   \
    acc0 = fmaf(__uint_as_float((W).x << 16), NS, acc0);              \
    acc1 = fmaf(__uint_as_float((W).x & 0xffff0000u), NS, acc1);      \
    acc2 = fmaf(__uint_as_float((W).y << 16), NS, acc2);              \
    acc3 = fmaf(__uint_as_float((W).y & 0xffff0000u), NS, acc3);      \
    acc4 = fmaf(__uint_as_float((W).z << 16), NS, acc4);              \
    acc5 = fmaf(__uint_as_float((W).z & 0xffff0000u), NS, acc5);      \
    acc6 = fmaf(__uint_as_float((W).w << 16), NS, acc6);              \
    acc7 = fmaf(__uint_as_float((W).w & 0xffff0000u), NS, acc7);

__global__ __launch_bounds__(256) void agg1_kernel(
    const int* __restrict__ offsets, const unsigned short* __restrict__ sorted_src,
    const unsigned short* __restrict__ Hb, const float* __restrict__ norm_dst,
    const float* __restrict__ norm_src, const float* __restrict__ b1,
    unsigned short* __restrict__ H1h, unsigned short* __restrict__ H1l) {
    int wid = (blockIdx.x * 256 + threadIdx.x) >> 6;
    int lane = threadIdx.x & 63;
    if (wid >= N_NODES) return;
    int start = offsets[wid], end = offsets[wid + 1];
    int quad = lane >> 4;
    int c8 = (lane & 15) * 8;
    float acc0 = 0.f, acc1 = 0.f, acc2 = 0.f, acc3 = 0.f;
    float acc4 = 0.f, acc5 = 0.f, acc6 = 0.f, acc7 = 0.f;
    int base = start;
    for (; base + 16 <= end; base += 16) {
        int e0 = sorted_src[base + quad];
        int e1 = sorted_src[base + 4 + quad];
        int e2 = sorted_src[base + 8 + quad];
        int e3 = sorted_src[base + 12 + quad];
        float n0 = norm_src[e0], n1 = norm_src[e1];
        float n2 = norm_src[e2], n3 = norm_src[e3];
        uint4 w0 = *(const uint4*)&Hb[(size_t)e0 * N_HIDDEN + c8];
        uint4 w1 = *(const uint4*)&Hb[(size_t)e1 * N_HIDDEN + c8];
        uint4 w2 = *(const uint4*)&Hb[(size_t)e2 * N_HIDDEN + c8];
        uint4 w3 = *(const uint4*)&Hb[(size_t)e3 * N_HIDDEN + c8];
        FMA8(w0, n0);
        FMA8(w1, n1);
        FMA8(w2, n2);
        FMA8(w3, n3);
    }
    for (; base + 4 <= end; base += 4) {
        int e = sorted_src[base + quad];
        float n = norm_src[e];
        uint4 w = *(const uint4*)&Hb[(size_t)e * N_HIDDEN + c8];
        FMA8(w, n);
    }
    int rem = end - base;
    if (quad < rem) {
        int e = sorted_src[base + quad];
        float n = norm_src[e];
        uint4 w = *(const uint4*)&Hb[(size_t)e * N_HIDDEN + c8];
        FMA8(w, n);
    }
    acc0 += __shfl_xor(acc0, 16); acc0 += __shfl_xor(acc0, 32);
    acc1 += __shfl_xor(acc1, 16); acc1 += __shfl_xor(acc1, 32);
    acc2 += __shfl_xor(acc2, 16); acc2 += __shfl_xor(acc2, 32);
    acc3 += __shfl_xor(acc3, 16); acc3 += __shfl_xor(acc3, 32);
    acc4 += __shfl_xor(acc4, 16); acc4 += __shfl_xor(acc4, 32);
    acc5 += __shfl_xor(acc5, 16); acc5 += __shfl_xor(acc5, 32);
    acc6 += __shfl_xor(acc6, 16); acc6 += __shfl_xor(acc6, 32);
    acc7 += __shfl_xor(acc7, 16); acc7 += __shfl_xor(acc7, 32);
    if (quad == 0) {
        float nd = norm_dst[wid];
        float ns = norm_src[wid];
        float4 ba = *(const float4*)&b1[c8];
        float4 bb = *(const float4*)&b1[c8 + 4];
        float o[8];
        o[0] = fmaxf(acc0 * nd + ba.x, 0.f) * ns;
        o[1] = fmaxf(acc1 * nd + ba.y, 0.f) * ns;
        o[2] = fmaxf(acc2 * nd + ba.z, 0.f) * ns;
        o[3] = fmaxf(acc3 * nd + ba.w, 0.f) * ns;
        o[4] = fmaxf(acc4 * nd + bb.x, 0.f) * ns;
        o[5] = fmaxf(acc5 * nd + bb.y, 0.f) * ns;
        o[6] = fmaxf(acc6 * nd + bb.z, 0.f) * ns;
        o[7] = fmaxf(acc7 * nd + bb.w, 0.f) * ns;
        unsigned short hh[8], ll[8];
#pragma unroll
        for (int t = 0; t < 8; t++) {
            hh[t] = f2bf(o[t]);
            ll[t] = f2bf(o[t] - bf2f(hh[t]));
        }
        uint4 ph = make_uint4((unsigned)hh[0] | ((unsigned)hh[1] << 16),
                              (unsigned)hh[2] | ((unsigned)hh[3] << 16),
                              (unsigned)hh[4] | ((unsigned)hh[5] << 16),
                              (unsigned)hh[6] | ((unsigned)hh[7] << 16));
        uint4 pl = make_uint4((unsigned)ll[0] | ((unsigned)ll[1] << 16),
                              (unsigned)ll[2] | ((unsigned)ll[3] << 16),
                              (unsigned)ll[4] | ((unsigned)ll[5] << 16),
                              (unsigned)ll[6] | ((unsigned)ll[7] << 16));
        *(uint4*)&H1h[(size_t)wid * N_HIDDEN + c8] = ph;
        *(uint4*)&H1l[(size_t)wid * N_HIDDEN + c8] = pl;
    }
}

// ---------------------------------------------------------------------------
// GEMM2 via bf16 MFMA: H2u[n][0:40] = H1n @ W2, PACKED hi|lo bf16 in u32
// (full f32 precision to 2^-17 rel), 48-dword rows for 16B-aligned gathers.
__global__ __launch_bounds__(256) void gemm2_kernel(
    const unsigned short* __restrict__ H1h, const unsigned short* __restrict__ H1l,
    const unsigned short* __restrict__ W2th, const unsigned short* __restrict__ W2tl,
    unsigned int* __restrict__ H2u) {
    __shared__ __align__(16) unsigned short Bh[48][136];
    __shared__ __align__(16) unsigned short Bl[48][136];
    const int tid = threadIdx.x;
    for (int i = tid; i < 48 * 16; i += 256) {
        int n = i >> 4, kq = (i & 15) * 8;
        *(uint4*)&Bh[n][kq] = *(const uint4*)&W2th[n * 128 + kq];
        *(uint4*)&Bl[n][kq] = *(const uint4*)&W2tl[n * 128 + kq];
    }
    __syncthreads();
    const int lane = tid & 63;
    const int wave = tid >> 6;
    const int m = lane & 15;
    const int q = lane >> 4;
    const int row0 = blockIdx.x * 128 + wave * 32;

    f32x4 acc[2][3];
#pragma unroll
    for (int i = 0; i < 2; i++)
#pragma unroll
        for (int j = 0; j < 3; j++) acc[i][j] = (f32x4){0.f, 0.f, 0.f, 0.f};

#pragma unroll
    for (int kc = 0; kc < 4; kc++) {
        bf16x8 bh[3], bl[3];
#pragma unroll
        for (int j = 0; j < 3; j++) {
            bh[j] = *(const bf16x8*)&Bh[j * 16 + m][kc * 32 + q * 8];
            bl[j] = *(const bf16x8*)&Bl[j * 16 + m][kc * 32 + q * 8];
        }
#pragma unroll
        for (int i = 0; i < 2; i++) {
            size_t ro = (size_t)(row0 + i * 16 + m) * N_HIDDEN + kc * 32 + q * 8;
            bf16x8 ah = *(const bf16x8*)&H1h[ro];
            bf16x8 al = *(const bf16x8*)&H1l[ro];
#pragma unroll
            for (int j = 0; j < 3; j++) {
                acc[i][j] = __builtin_amdgcn_mfma_f32_16x16x32_bf16(ah, bh[j], acc[i][j], 0, 0, 0);
                acc[i][j] = __builtin_amdgcn_mfma_f32_16x16x32_bf16(ah, bl[j], acc[i][j], 0, 0, 0);
                acc[i][j] = __builtin_amdgcn_mfma_f32_16x16x32_bf16(al, bh[j], acc[i][j], 0, 0, 0);
            }
        }
    }
#pragma unroll
    for (int i = 0; i < 2; i++) {
#pragma unroll
        for (int r = 0; r < 4; r++) {
            int row = row0 + i * 16 + q * 4 + r;
            if (row < N_NODES) {
#pragma unroll
                for (int j = 0; j < 3; j++) {
                    int col = j * 16 + m;
                    if (col < N_CLASSES) {
                        float v = acc[i][j][r];
                        unsigned short h = f2bf(v);
                        unsigned short l = f2bf(v - bf2f(h));
                        H2u[(size_t)row * 48 + col] = ((unsigned)h << 16) | (unsigned)l;
                    }
                }
            }
        }
    }
}

// ---------------------------------------------------------------------------
// agg2: one wave per dst node; 16 edges in flight (4 uint4/lane), packed
// hi|lo bf16 reconstruction, butterfly reduce.
#define ACC4(V)                                                               \
    acc.x += __uint_as_float((V).x & 0xffff0000u) + __uint_as_float((V).x << 16); \
    acc.y += __uint_as_float((V).y & 0xffff0000u) + __uint_as_float((V).y << 16); \
    acc.z += __uint_as_float((V).z & 0xffff0000u) + __uint_as_float((V).z << 16); \
    acc.w += __uint_as_float((V).w & 0xffff0000u) + __uint_as_float((V).w << 16);

__global__ __launch_bounds__(256) void agg2_kernel(
    const int* __restrict__ offsets, const unsigned short* __restrict__ sorted_src,
    const unsigned int* __restrict__ H2u, const float* __restrict__ norm_dst,
    const float* __restrict__ b2, float* __restrict__ OUT) {
    int wid = (blockIdx.x * 256 + threadIdx.x) >> 6;
    int lane = threadIdx.x & 63;
    if (wid >= N_NODES) return;
    int start = offsets[wid], end = offsets[wid + 1];
    int quad = lane >> 4;
    int c4 = (lane & 15) * 4;
    bool active = c4 < N_CLASSES;
    float4 acc = make_float4(0.f, 0.f, 0.f, 0.f);
    int base = start;
    for (; base + 16 <= end; base += 16) {
        int e0 = sorted_src[base + quad];
        int e1 = sorted_src[base + 4 + quad];
        int e2 = sorted_src[base + 8 + quad];
        int e3 = sorted_src[base + 12 + quad];
        if (active) {
            uint4 v0 = *(const uint4*)&H2u[(size_t)e0 * 48 + c4];
            uint4 v1 = *(const uint4*)&H2u[(size_t)e1 * 48 + c4];
            uint4 v2 = *(const uint4*)&H2u[(size_t)e2 * 48 + c4];
            uint4 v3 = *(const uint4*)&H2u[(size_t)e3 * 48 + c4];
            ACC4(v0); ACC4(v1); ACC4(v2); ACC4(v3);
        }
    }
    for (; base + 4 <= end; base += 4) {
        int e = sorted_src[base + quad];
        if (active) {
            uint4 v = *(const uint4*)&H2u[(size_t)e * 48 + c4];
            ACC4(v);
        }
    }
    int rem = end - base;
    if (quad < rem && active) {
        int e = sorted_src[base + quad];
        uint4 v = *(const uint4*)&H2u[(size_t)e * 48 + c4];
        ACC4(v);
    }
    acc.x += __shfl_xor(acc.x, 16); acc.x += __shfl_xor(acc.x, 32);
    acc.y += __shfl_xor(acc.y, 16); acc.y += __shfl_xor(acc.y, 32);
    acc.z += __shfl_xor(acc.z, 16); acc.z += __shfl_xor(acc.z, 32);
    acc.w += __shfl_xor(acc.w, 16); acc.w += __shfl_xor(acc.w, 32);
    if (lane < 10) {
        float nd = norm_dst[wid];
        float4 b = *(const float4*)&b2[lane * 4];
        acc.x = acc.x * nd + b.x;
        acc.y = acc.y * nd + b.y;
        acc.z = acc.z * nd + b.z;
        acc.w = acc.w * nd + b.w;
        *(float4*)&OUT[(size_t)wid * N_CLASSES + lane * 4] = acc;
    }
}

// ---------------------------------------------------------------------------
extern "C" void kernel_launch(void* const* d_in, const int* in_sizes, int n_in,
                              void* d_out, int out_size, void* d_ws, size_t ws_size,
                              hipStream_t stream) {
    const float* X   = (const float*)d_in[0];
    const float* W1  = (const float*)d_in[1];
    const float* b1  = (const float*)d_in[2];
    const float* W2  = (const float*)d_in[3];
    const float* b2  = (const float*)d_in[4];
    const int*   src = (const int*)d_in[5];
    const int*   dst = (const int*)d_in[6];
    float* out = (float*)d_out;

    // workspace layout (4B units). regionA time-shared:
    //   phase 1: histD|histS|baseD|baseS|totD|totS      [dead after p3]
    //   phase 3: H2u packed u32 50000x48 (2.4M dwords)  [written at gemm2]
    // Hb has its own region (written by megaA while phase-1 data live).
    float* norm_src   = (float*)d_ws;                     // 50000
    float* norm_dst   = norm_src + N_NODES;               // 50000
    int*   offsets    = (int*)(norm_dst + N_NODES);       // 50016 (incl pad)
    int*   bucket_base = offsets + N_NODES + 16;          // 800
    int*   srcb_base  = bucket_base + 800;                // 800
    unsigned int* edata = (unsigned int*)(srcb_base + 800);       // 1.6M
    unsigned char* srcv = (unsigned char*)(edata + N_EDGES);      // 400K dwords
    unsigned short* sorted_src =
        (unsigned short*)((int*)(edata + N_EDGES) + 400000);      // 1.6M ushort
    int*   regionA    = (int*)(edata + N_EDGES) + 400000 + 800000; // 3.2M dwords
    int*   histD      = regionA;
    int*   histS      = regionA + 625600;
    int*   baseD      = regionA + 1251200;
    int*   baseS      = regionA + 1876800;
    int*   totD       = regionA + 2502400;                // 800
    int*   totS       = regionA + 2503200;                // 800
    unsigned int* H2u = (unsigned int*)regionA;           // phase 3 (2.4M)
    unsigned short* H1h = (unsigned short*)(regionA + 3200000);   // 50048x128 bf16
    unsigned short* H1l = H1h + (size_t)NROWPAD * N_HIDDEN;
    unsigned short* W1ch = H1l + (size_t)NROWPAD * N_HIDDEN;      // k-chunked 512*128
    unsigned short* W1cl = W1ch + IN_FEATS * N_HIDDEN;
    unsigned short* W2th = W1cl + IN_FEATS * N_HIDDEN;            // 48*128
    unsigned short* W2tl = W2th + 48 * 128;
    unsigned short* Hb   = W2tl + 48 * 128;               // 50000x128 bf16 (own region)

    setup_cvt<<<(IN_FEATS * N_HIDDEN + 48 * 128) / 256, 256, 0, stream>>>(
        W1, W2, W1ch, W1cl, W2th, W2tl);
    megaA<<<NBLK + NBKT, 256, 0, stream>>>(src, dst, histD, histS, X, W1ch, W1cl, Hb);
    p2_local<<<(NBKT + 3) / 4, 256, 0, stream>>>(histD, histS, baseD, baseS, totD, totS);
    p2_small<<<1, 1024, 0, stream>>>(totD, totS, bucket_base, srcb_base, offsets);
    p3_scatter<<<NBLK, 256, 0, stream>>>(src, dst, baseD, baseS, bucket_base, srcb_base,
                                         edata, srcv);
    p4_fused<<<NBKT, 256, 0, stream>>>(srcb_base, srcv, bucket_base, edata,
                                       offsets, norm_src, norm_dst, sorted_src);
    agg1_kernel<<<(N_NODES + 3) / 4, 256, 0, stream>>>(offsets, sorted_src, Hb, norm_dst,
                                                       norm_src, b1, H1h, H1l);
    gemm2_kernel<<<(N_NODES + 127) / 128, 256, 0, stream>>>(H1h, H1l, W2th, W2tl, H2u);
    agg2_kernel<<<(N_NODES + 3) / 4, 256, 0, stream>>>(offsets, sorted_src, H2u, norm_dst, b2, out);
}